// Round 1
// baseline (1708.364 us; speedup 1.0000x reference)
//
#include <hip/hip_runtime.h>
#include <cstdint>
#include <cstddef>

// Problem constants (fixed by the reference)
static constexpr int NN = 100000;   // nodes
static constexpr int NE = 3200000;  // edges
static constexpr int NG = 256;      // graphs
static constexpr int NB = (NN + 1023) / 1024;  // scan blocks = 98

__device__ __forceinline__ void atomAddF(float* p, float v) {
  unsafeAtomicAdd(p, v);  // native global_atomic_add_f32 on gfx950
}

// ---------------------------------------------------------------------------
// dtype hedge: reference says int64, harness doc says int32. Detect at runtime.
// If edge_index really is int64 (little-endian), every odd 32-bit word of the
// first 64 entries is 0 (node ids < 2^31). Probability of false positive with
// genuine int32 data: (1e-5)^64 ~ 0.
__global__ void k_detect(const int* __restrict__ ei, int* __restrict__ flag) {
  if (threadIdx.x == 0 && blockIdx.x == 0) {
    int nz = 0;
    for (int i = 0; i < 64; ++i) nz += (ei[2 * i + 1] != 0) ? 1 : 0;
    *flag = (nz == 0) ? 1 : 0;  // 1 => int64 layout
  }
}

__global__ void k_repack_edges(const void* __restrict__ ei_raw,
                               const int* __restrict__ flag,
                               int* __restrict__ sd) {
  int i = blockIdx.x * 256 + threadIdx.x;
  if (i >= 2 * NE) return;
  if (*flag) sd[i] = (int)((const long long*)ei_raw)[i];
  else       sd[i] = ((const int*)ei_raw)[i];
}

__global__ void k_repack_batch(const void* __restrict__ b_raw,
                               const int* __restrict__ flag,
                               int* __restrict__ b32) {
  int i = blockIdx.x * 256 + threadIdx.x;
  if (i >= NN) return;
  if (*flag) b32[i] = (int)((const long long*)b_raw)[i];
  else       b32[i] = ((const int*)b_raw)[i];
}

// ---------------------------------------------------------------------------
// CSR build: out-degree (for dinv) + in-degree histogram, scan, fill.
__global__ void k_count(const int* __restrict__ sd,
                        int* __restrict__ deg, int* __restrict__ indeg) {
  int e = blockIdx.x * 256 + threadIdx.x;
  if (e < NE) {
    atomicAdd(&deg[sd[e]], 1);        // src
    atomicAdd(&indeg[sd[NE + e]], 1); // dst
  }
}

__global__ void k_dinv_gcnt(const int* __restrict__ deg,
                            const int* __restrict__ b32,
                            float* __restrict__ dinv, int* __restrict__ gcnt) {
  int i = blockIdx.x * 256 + threadIdx.x;
  if (i < NN) {
    int dg = deg[i];
    dinv[i] = (dg > 0) ? rsqrtf((float)dg) : 0.f;
    atomicAdd(&gcnt[b32[i]], 1);
  }
}

__global__ __launch_bounds__(1024) void k_scan1(const int* __restrict__ indeg,
                                                int* __restrict__ rowptr,
                                                int* __restrict__ bsum) {
  __shared__ int sh[1024];
  int t = threadIdx.x;
  int i = blockIdx.x * 1024 + t;
  int v = (i < NN) ? indeg[i] : 0;
  sh[t] = v;
  __syncthreads();
  for (int off = 1; off < 1024; off <<= 1) {
    int a = (t >= off) ? sh[t - off] : 0;
    __syncthreads();
    sh[t] += a;
    __syncthreads();
  }
  if (i < NN) rowptr[i + 1] = sh[t];  // inclusive, shifted to +1
  if (t == 1023) bsum[blockIdx.x] = sh[t];
}

__global__ void k_scan2(const int* __restrict__ bsum, int* __restrict__ boff,
                        int* __restrict__ rowptr) {
  __shared__ int sh[128];
  int t = threadIdx.x;
  int v = (t < NB) ? bsum[t] : 0;
  sh[t] = v;
  __syncthreads();
  for (int off = 1; off < 128; off <<= 1) {
    int a = (t >= off) ? sh[t - off] : 0;
    __syncthreads();
    sh[t] += a;
    __syncthreads();
  }
  if (t < NB) boff[t] = sh[t] - v;  // exclusive block offsets
  if (t == 0) rowptr[0] = 0;
}

__global__ __launch_bounds__(1024) void k_scan3(int* __restrict__ rowptr,
                                                const int* __restrict__ boff) {
  int i = blockIdx.x * 1024 + threadIdx.x;
  if (i < NN) rowptr[i + 1] += boff[blockIdx.x];
}

__global__ void k_fill(const int* __restrict__ sd, const float* __restrict__ dinv,
                       const int* __restrict__ rowptr, int* __restrict__ fill,
                       int2* __restrict__ ed) {
  int e = blockIdx.x * 256 + threadIdx.x;
  if (e < NE) {
    int s = sd[e], d = sd[NE + e];
    float w = -dinv[s] * dinv[d];
    int pos = rowptr[d] + atomicAdd(&fill[d], 1);
    ed[pos] = make_int2(s, __float_as_int(w));
  }
}

// ---------------------------------------------------------------------------
// Propagation: out[i][d] = sum over incoming edges (w * in[src][d]), D=64.
// One wave per node (lane = dim), 4 nodes per 256-thread block.
__global__ __launch_bounds__(256) void k_prop(const int* __restrict__ rp,
                                              const int2* __restrict__ ed,
                                              const float* __restrict__ vin,
                                              float* __restrict__ vout) {
  int node = blockIdx.x * 4 + (threadIdx.x >> 6);
  int d = threadIdx.x & 63;
  if (node >= NN) return;
  int p0 = rp[node], p1 = rp[node + 1];
  float a0 = 0.f, a1 = 0.f;
  int p = p0;
  for (; p + 2 <= p1; p += 2) {  // 2 independent chains for MLP
    int2 e0 = ed[p];
    int2 e1 = ed[p + 1];
    a0 += __int_as_float(e0.y) * vin[(size_t)e0.x * 64 + d];
    a1 += __int_as_float(e1.y) * vin[(size_t)e1.x * 64 + d];
  }
  if (p < p1) {
    int2 e = ed[p];
    a0 += __int_as_float(e.y) * vin[(size_t)e.x * 64 + d];
  }
  vout[(size_t)node * 64 + d] = a0 + a1;
}

// ---------------------------------------------------------------------------
// GEMM A: U1 = x @ W1[1], U2 = x @ W1[2].  x:[NN,128], W slices [128,64].
// Tile: 128 nodes x 64 dims, 256 threads, microtile 8 nodes x 4 dims.
__global__ __launch_bounds__(256) void k_gemm_u(const float* __restrict__ x,
                                                const float* __restrict__ W1,
                                                float* __restrict__ U1,
                                                float* __restrict__ U2) {
  __shared__ __align__(16) float Xs[16][132];
  __shared__ __align__(16) float Ws1[16][64];
  __shared__ __align__(16) float Ws2[16][64];
  const int t = threadIdx.x;
  const int d4 = (t & 15) * 4;
  const int ng = t >> 4;
  const int n0 = blockIdx.x * 128;
  float acc1[8][4], acc2[8][4];
#pragma unroll
  for (int j = 0; j < 8; ++j)
#pragma unroll
    for (int c = 0; c < 4; ++c) { acc1[j][c] = 0.f; acc2[j][c] = 0.f; }

  for (int kc = 0; kc < 128; kc += 16) {
#pragma unroll
    for (int u = 0; u < 2; ++u) {
      int lin = t * 2 + u;
      int i = lin >> 2, q = lin & 3;
      int row = n0 + i;
      float4 v = make_float4(0.f, 0.f, 0.f, 0.f);
      if (row < NN) v = *reinterpret_cast<const float4*>(x + (size_t)row * 128 + kc + q * 4);
      int k0 = q * 4;
      Xs[k0 + 0][i] = v.x; Xs[k0 + 1][i] = v.y; Xs[k0 + 2][i] = v.z; Xs[k0 + 3][i] = v.w;
    }
    {
      int kk = t >> 4, dq = (t & 15) * 4;
      float4 a = *reinterpret_cast<const float4*>(W1 + (size_t)(128 + kc + kk) * 64 + dq);
      float4 b = *reinterpret_cast<const float4*>(W1 + (size_t)(256 + kc + kk) * 64 + dq);
      *reinterpret_cast<float4*>(&Ws1[kk][dq]) = a;
      *reinterpret_cast<float4*>(&Ws2[kk][dq]) = b;
    }
    __syncthreads();
#pragma unroll
    for (int kk = 0; kk < 16; ++kk) {
      float4 xa = *reinterpret_cast<const float4*>(&Xs[kk][ng * 8]);
      float4 xb = *reinterpret_cast<const float4*>(&Xs[kk][ng * 8 + 4]);
      float4 w1 = *reinterpret_cast<const float4*>(&Ws1[kk][d4]);
      float4 w2 = *reinterpret_cast<const float4*>(&Ws2[kk][d4]);
      float xr[8] = {xa.x, xa.y, xa.z, xa.w, xb.x, xb.y, xb.z, xb.w};
      float w1r[4] = {w1.x, w1.y, w1.z, w1.w};
      float w2r[4] = {w2.x, w2.y, w2.z, w2.w};
#pragma unroll
      for (int j = 0; j < 8; ++j)
#pragma unroll
        for (int c = 0; c < 4; ++c) {
          acc1[j][c] += xr[j] * w1r[c];
          acc2[j][c] += xr[j] * w2r[c];
        }
    }
    __syncthreads();
  }
#pragma unroll
  for (int j = 0; j < 8; ++j) {
    int row = n0 + ng * 8 + j;
    if (row < NN) {
      float4 v1 = make_float4(acc1[j][0], acc1[j][1], acc1[j][2], acc1[j][3]);
      float4 v2 = make_float4(acc2[j][0], acc2[j][1], acc2[j][2], acc2[j][3]);
      *reinterpret_cast<float4*>(U1 + (size_t)row * 64 + d4) = v1;
      *reinterpret_cast<float4*>(U2 + (size_t)row * 64 + d4) = v2;
    }
  }
}

// GEMM B: h1 = relu(x @ (W1[0]-W1[2]) + P + 2R + b1)
__global__ __launch_bounds__(256) void k_gemm_h1(const float* __restrict__ x,
                                                 const float* __restrict__ W1,
                                                 const float* __restrict__ b1v,
                                                 const float* __restrict__ P,
                                                 const float* __restrict__ R,
                                                 float* __restrict__ h1) {
  __shared__ __align__(16) float Xs[16][132];
  __shared__ __align__(16) float Ws[16][64];
  const int t = threadIdx.x;
  const int d4 = (t & 15) * 4;
  const int ng = t >> 4;
  const int n0 = blockIdx.x * 128;
  float acc[8][4];
#pragma unroll
  for (int j = 0; j < 8; ++j)
#pragma unroll
    for (int c = 0; c < 4; ++c) acc[j][c] = 0.f;

  for (int kc = 0; kc < 128; kc += 16) {
#pragma unroll
    for (int u = 0; u < 2; ++u) {
      int lin = t * 2 + u;
      int i = lin >> 2, q = lin & 3;
      int row = n0 + i;
      float4 v = make_float4(0.f, 0.f, 0.f, 0.f);
      if (row < NN) v = *reinterpret_cast<const float4*>(x + (size_t)row * 128 + kc + q * 4);
      int k0 = q * 4;
      Xs[k0 + 0][i] = v.x; Xs[k0 + 1][i] = v.y; Xs[k0 + 2][i] = v.z; Xs[k0 + 3][i] = v.w;
    }
    {
      int kk = t >> 4, dq = (t & 15) * 4;
      float4 a = *reinterpret_cast<const float4*>(W1 + (size_t)(kc + kk) * 64 + dq);
      float4 c = *reinterpret_cast<const float4*>(W1 + (size_t)(256 + kc + kk) * 64 + dq);
      float4 wv = make_float4(a.x - c.x, a.y - c.y, a.z - c.z, a.w - c.w);
      *reinterpret_cast<float4*>(&Ws[kk][dq]) = wv;
    }
    __syncthreads();
#pragma unroll
    for (int kk = 0; kk < 16; ++kk) {
      float4 xa = *reinterpret_cast<const float4*>(&Xs[kk][ng * 8]);
      float4 xb = *reinterpret_cast<const float4*>(&Xs[kk][ng * 8 + 4]);
      float4 w = *reinterpret_cast<const float4*>(&Ws[kk][d4]);
      float xr[8] = {xa.x, xa.y, xa.z, xa.w, xb.x, xb.y, xb.z, xb.w};
      float wr[4] = {w.x, w.y, w.z, w.w};
#pragma unroll
      for (int j = 0; j < 8; ++j)
#pragma unroll
        for (int c = 0; c < 4; ++c) acc[j][c] += xr[j] * wr[c];
    }
    __syncthreads();
  }
  float4 bv = *reinterpret_cast<const float4*>(b1v + d4);
#pragma unroll
  for (int j = 0; j < 8; ++j) {
    int row = n0 + ng * 8 + j;
    if (row < NN) {
      float4 pv = *reinterpret_cast<const float4*>(P + (size_t)row * 64 + d4);
      float4 rv = *reinterpret_cast<const float4*>(R + (size_t)row * 64 + d4);
      float4 o;
      o.x = fmaxf(acc[j][0] + pv.x + 2.f * rv.x + bv.x, 0.f);
      o.y = fmaxf(acc[j][1] + pv.y + 2.f * rv.y + bv.y, 0.f);
      o.z = fmaxf(acc[j][2] + pv.z + 2.f * rv.z + bv.z, 0.f);
      o.w = fmaxf(acc[j][3] + pv.w + 2.f * rv.w + bv.w, 0.f);
      *reinterpret_cast<float4*>(h1 + (size_t)row * 64 + d4) = o;
    }
  }
}

// GEMM C: h2 = relu(h1@(W2[0]-W2[2]) + T1@W2[1] + T2@(2*W2[2]) + b2),
// fused segmented mean-pool numerator (batch sorted) into pooled[] atomics.
__global__ __launch_bounds__(256) void k_gemm_h2_pool(const float* __restrict__ h1,
                                                      const float* __restrict__ T1,
                                                      const float* __restrict__ T2,
                                                      const float* __restrict__ W2,
                                                      const float* __restrict__ b2v,
                                                      const int* __restrict__ b32,
                                                      float* __restrict__ pooled) {
  __shared__ __align__(16) float smem[9408];  // 3*16*132 + 3*16*64
  __shared__ int gb[128];
  float (*Xh)[132]  = reinterpret_cast<float (*)[132]>(smem);
  float (*Xt1)[132] = reinterpret_cast<float (*)[132]>(smem + 2112);
  float (*Xt2)[132] = reinterpret_cast<float (*)[132]>(smem + 4224);
  float (*Wa)[64]   = reinterpret_cast<float (*)[64]>(smem + 6336);
  float (*Wb)[64]   = reinterpret_cast<float (*)[64]>(smem + 7360);
  float (*Wc)[64]   = reinterpret_cast<float (*)[64]>(smem + 8384);
  float (*ht)[68]   = reinterpret_cast<float (*)[68]>(smem);  // aliases Xs after K-loop

  const int t = threadIdx.x;
  const int d4 = (t & 15) * 4;
  const int ng = t >> 4;
  const int n0 = blockIdx.x * 128;
  if (t < 128) gb[t] = (n0 + t < NN) ? b32[n0 + t] : -1;

  float acc[8][4];
#pragma unroll
  for (int j = 0; j < 8; ++j)
#pragma unroll
    for (int c = 0; c < 4; ++c) acc[j][c] = 0.f;

  for (int kc = 0; kc < 64; kc += 16) {
#pragma unroll
    for (int u = 0; u < 2; ++u) {
      int lin = t * 2 + u;
      int i = lin >> 2, q = lin & 3;
      int row = n0 + i;
      float4 vh = make_float4(0.f, 0.f, 0.f, 0.f), v1 = vh, v2 = vh;
      if (row < NN) {
        vh = *reinterpret_cast<const float4*>(h1 + (size_t)row * 64 + kc + q * 4);
        v1 = *reinterpret_cast<const float4*>(T1 + (size_t)row * 64 + kc + q * 4);
        v2 = *reinterpret_cast<const float4*>(T2 + (size_t)row * 64 + kc + q * 4);
      }
      int k0 = q * 4;
      Xh[k0 + 0][i] = vh.x; Xh[k0 + 1][i] = vh.y; Xh[k0 + 2][i] = vh.z; Xh[k0 + 3][i] = vh.w;
      Xt1[k0 + 0][i] = v1.x; Xt1[k0 + 1][i] = v1.y; Xt1[k0 + 2][i] = v1.z; Xt1[k0 + 3][i] = v1.w;
      Xt2[k0 + 0][i] = v2.x; Xt2[k0 + 1][i] = v2.y; Xt2[k0 + 2][i] = v2.z; Xt2[k0 + 3][i] = v2.w;
    }
    {
      int kk = t >> 4, dq = (t & 15) * 4;
      float4 w0 = *reinterpret_cast<const float4*>(W2 + (size_t)(kc + kk) * 64 + dq);
      float4 w1 = *reinterpret_cast<const float4*>(W2 + 4096 + (size_t)(kc + kk) * 64 + dq);
      float4 w2 = *reinterpret_cast<const float4*>(W2 + 8192 + (size_t)(kc + kk) * 64 + dq);
      float4 wa = make_float4(w0.x - w2.x, w0.y - w2.y, w0.z - w2.z, w0.w - w2.w);
      float4 wc = make_float4(2.f * w2.x, 2.f * w2.y, 2.f * w2.z, 2.f * w2.w);
      *reinterpret_cast<float4*>(&Wa[kk][dq]) = wa;
      *reinterpret_cast<float4*>(&Wb[kk][dq]) = w1;
      *reinterpret_cast<float4*>(&Wc[kk][dq]) = wc;
    }
    __syncthreads();
#pragma unroll
    for (int kk = 0; kk < 16; ++kk) {
      float4 ha = *reinterpret_cast<const float4*>(&Xh[kk][ng * 8]);
      float4 hb = *reinterpret_cast<const float4*>(&Xh[kk][ng * 8 + 4]);
      float4 p1a = *reinterpret_cast<const float4*>(&Xt1[kk][ng * 8]);
      float4 p1b = *reinterpret_cast<const float4*>(&Xt1[kk][ng * 8 + 4]);
      float4 p2a = *reinterpret_cast<const float4*>(&Xt2[kk][ng * 8]);
      float4 p2b = *reinterpret_cast<const float4*>(&Xt2[kk][ng * 8 + 4]);
      float4 wa = *reinterpret_cast<const float4*>(&Wa[kk][d4]);
      float4 wb = *reinterpret_cast<const float4*>(&Wb[kk][d4]);
      float4 wc = *reinterpret_cast<const float4*>(&Wc[kk][d4]);
      float hr[8] = {ha.x, ha.y, ha.z, ha.w, hb.x, hb.y, hb.z, hb.w};
      float r1[8] = {p1a.x, p1a.y, p1a.z, p1a.w, p1b.x, p1b.y, p1b.z, p1b.w};
      float r2[8] = {p2a.x, p2a.y, p2a.z, p2a.w, p2b.x, p2b.y, p2b.z, p2b.w};
      float war[4] = {wa.x, wa.y, wa.z, wa.w};
      float wbr[4] = {wb.x, wb.y, wb.z, wb.w};
      float wcr[4] = {wc.x, wc.y, wc.z, wc.w};
#pragma unroll
      for (int j = 0; j < 8; ++j)
#pragma unroll
        for (int c = 0; c < 4; ++c)
          acc[j][c] += hr[j] * war[c] + r1[j] * wbr[c] + r2[j] * wcr[c];
    }
    __syncthreads();
  }
  // epilogue: relu + bias into LDS tile (aliased over Xs, safe after barrier)
  float4 bv = *reinterpret_cast<const float4*>(b2v + d4);
#pragma unroll
  for (int j = 0; j < 8; ++j) {
    int r = ng * 8 + j;
    float4 o;
    o.x = fmaxf(acc[j][0] + bv.x, 0.f);
    o.y = fmaxf(acc[j][1] + bv.y, 0.f);
    o.z = fmaxf(acc[j][2] + bv.z, 0.f);
    o.w = fmaxf(acc[j][3] + bv.w, 0.f);
    *reinterpret_cast<float4*>(&ht[r][d4]) = o;
  }
  __syncthreads();
  // segmented pool: batch sorted -> run-length reduce 32 rows per quarter-block
  int rg = t >> 6;
  int d = t & 63;
  int base = rg * 32;
  int cur = -2;
  float s = 0.f;
  for (int i2 = 0; i2 < 32; ++i2) {
    int g = gb[base + i2];  // wave-uniform
    if (g != cur) {
      if (cur >= 0) atomAddF(&pooled[cur * 64 + d], s);
      s = 0.f;
      cur = g;
    }
    if (g >= 0) s += ht[base + i2][d];
  }
  if (cur >= 0) atomAddF(&pooled[cur * 64 + d], s);
}

// Final: out[g] = dot(pooled[g]/max(cnt,1), Wfc) + bfc
__global__ void k_out(const float* __restrict__ pooled, const int* __restrict__ gcnt,
                      const float* __restrict__ Wfc, const float* __restrict__ bfc,
                      float* __restrict__ out) {
  int g = blockIdx.x, t = threadIdx.x;  // 64 threads
  float v = pooled[g * 64 + t] * Wfc[t];
  int c = gcnt[g];
  v /= (float)(c > 0 ? c : 1);
  for (int off = 32; off > 0; off >>= 1) v += __shfl_down(v, off, 64);
  if (t == 0) out[g] = v + bfc[0];
}

// ---------------------------------------------------------------------------
extern "C" void kernel_launch(void* const* d_in, const int* in_sizes, int n_in,
                              void* d_out, int out_size, void* d_ws, size_t ws_size,
                              hipStream_t stream) {
  const float* x   = (const float*)d_in[0];
  const void*  ei  = d_in[1];
  const void*  bat = d_in[2];
  const float* W1  = (const float*)d_in[3];
  const float* b1v = (const float*)d_in[4];
  const float* W2  = (const float*)d_in[5];
  const float* b2v = (const float*)d_in[6];
  const float* Wfc = (const float*)d_in[7];
  const float* bfc = (const float*)d_in[8];
  float* out = (float*)d_out;

  char* w = (char*)d_ws;
  size_t o = 0;
  auto take = [&](size_t bytes) -> void* {
    void* p = w + o;
    o = (o + bytes + 255) & ~(size_t)255;
    return p;
  };
  int*   flag   = (int*)take(256);
  int*   deg    = (int*)take((size_t)NN * 4);   // ---- zero region start
  int*   indeg  = (int*)take((size_t)NN * 4);
  int*   fillc  = (int*)take((size_t)NN * 4);
  int*   gcnt   = (int*)take((size_t)NG * 4);
  float* pooled = (float*)take((size_t)NG * 64 * 4);
  int*   bsum   = (int*)take(512);
  int*   boff   = (int*)take(512);              // ---- zero region end
  int*   rowptr = (int*)take((size_t)(NN + 1) * 4);
  float* dinv   = (float*)take((size_t)NN * 4);
  int*   sd     = (int*)take((size_t)2 * NE * 4);
  int*   b32    = (int*)take((size_t)NN * 4);
  int2*  edata  = (int2*)take((size_t)NE * 8);
  float* f0     = (float*)take((size_t)NN * 64 * 4);
  float* f1     = (float*)take((size_t)NN * 64 * 4);
  float* f2     = (float*)take((size_t)NN * 64 * 4);
  float* f3     = (float*)take((size_t)NN * 64 * 4);
  (void)in_sizes; (void)n_in; (void)out_size; (void)ws_size;

  hipMemsetAsync(deg, 0, (size_t)((char*)rowptr - (char*)deg), stream);

  k_detect<<<1, 64, 0, stream>>>((const int*)ei, flag);
  k_repack_edges<<<(2 * NE + 255) / 256, 256, 0, stream>>>(ei, flag, sd);
  k_repack_batch<<<(NN + 255) / 256, 256, 0, stream>>>(bat, flag, b32);
  k_count<<<(NE + 255) / 256, 256, 0, stream>>>(sd, deg, indeg);
  k_dinv_gcnt<<<(NN + 255) / 256, 256, 0, stream>>>(deg, b32, dinv, gcnt);
  k_scan1<<<NB, 1024, 0, stream>>>(indeg, rowptr, bsum);
  k_scan2<<<1, 128, 0, stream>>>(bsum, boff, rowptr);
  k_scan3<<<NB, 1024, 0, stream>>>(rowptr, boff);
  k_fill<<<(NE + 255) / 256, 256, 0, stream>>>(sd, dinv, rowptr, fillc, edata);

  const int gemm_grid = (NN + 127) / 128;  // 782
  const int prop_grid = (NN + 3) / 4;      // 25000

  // Layer 1 (projected to 64-d before propagation):
  k_gemm_u<<<gemm_grid, 256, 0, stream>>>(x, W1, f0, f1);          // U1, U2
  k_prop<<<prop_grid, 256, 0, stream>>>(rowptr, edata, f0, f2);    // P  = L U1
  k_prop<<<prop_grid, 256, 0, stream>>>(rowptr, edata, f1, f3);    // Q  = L U2
  k_prop<<<prop_grid, 256, 0, stream>>>(rowptr, edata, f3, f1);    // R  = L Q
  k_gemm_h1<<<gemm_grid, 256, 0, stream>>>(x, W1, b1v, f2, f1, f3);// h1 -> f3
  // Layer 2:
  k_prop<<<prop_grid, 256, 0, stream>>>(rowptr, edata, f3, f0);    // T1 = L h1
  k_prop<<<prop_grid, 256, 0, stream>>>(rowptr, edata, f0, f2);    // T2 = L T1
  k_gemm_h2_pool<<<gemm_grid, 256, 0, stream>>>(f3, f0, f2, W2, b2v, b32, pooled);
  k_out<<<NG, 64, 0, stream>>>(pooled, gcnt, Wfc, bfc, out);
}